// Round 1
// baseline (64.983 us; speedup 1.0000x reference)
//
#include <hip/hip_runtime.h>

#define EPSF 1e-4f

// Exact per-2x2-block computation matching the numpy reference, f32, with
// explicit round-to-nearest intrinsics so the compiler cannot fuse/contract
// (we must track np's rounding as closely as possible: the primary/secondary
// branches are discrete comparisons).
__device__ __forceinline__ float fuzzy_one(float v0, float v1, float v2, float v3) {
    // kmm[0] = (v1+v2)/2 ; kmm[1] = mean(v)   (np sums sequentially)
    float k0 = __fmul_rn(__fadd_rn(v1, v2), 0.5f);
    float s4 = __fadd_rn(__fadd_rn(__fadd_rn(v0, v1), v2), v3);
    float k1 = __fmul_rn(s4, 0.25f);
    float vavg = __fmul_rn(__fadd_rn(k0, k1), 0.5f);

    float o0 = fabsf(__fsub_rn(v0, vavg));
    float o1 = fabsf(__fsub_rn(v1, vavg));
    float o2 = fabsf(__fsub_rn(v2, vavg));
    float o3 = fabsf(__fsub_rn(v3, vavg));
    float sg0 = __fadd_rn(__fmul_rn(__fadd_rn(o1, o2), 0.5f), EPSF);
    float so4 = __fadd_rn(__fadd_rn(__fadd_rn(o0, o1), o2), o3);
    float sg1 = __fadd_rn(__fmul_rn(so4, 0.25f), EPSF);

    const float vv[4] = {v0, v1, v2, v3};
    const float km[2] = {k0, k1};
    const float sg[2] = {sg0, sg1};

    float p[2][4];
#pragma unroll
    for (int k = 0; k < 2; ++k) {
#pragma unroll
        for (int n = 0; n < 4; ++n) {
            float d = __fdiv_rn(__fsub_rn(vv[n], km[k]), sg[k]);
            // np: -0.5 * diff * diff  (left-assoc)
            p[k][n] = expf(__fmul_rn(__fmul_rn(-0.5f, d), d));
        }
    }

    // avg over k (2 elements) and max over k
    float a0 = __fmul_rn(__fadd_rn(p[0][0], p[1][0]), 0.5f);
    float a1 = __fmul_rn(__fadd_rn(p[0][1], p[1][1]), 0.5f);
    float a2 = __fmul_rn(__fadd_rn(p[0][2], p[1][2]), 0.5f);
    float a3 = __fmul_rn(__fadd_rn(p[0][3], p[1][3]), 0.5f);
    float pm0 = fmaxf(p[0][0], p[1][0]);
    float pm1 = fmaxf(p[0][1], p[1][1]);
    float pm2 = fmaxf(p[0][2], p[1][2]);
    float pm3 = fmaxf(p[0][3], p[1][3]);
    float thresh = fminf(fminf(fminf(pm0, pm1), pm2), pm3);

    bool primary = (a1 >= thresh);        // avg_pi[..., HH-1] vs thresh
    bool s_cond  = (sg1 < 0.001f);

    float num = __fadd_rn(__fadd_rn(__fadd_rn(__fmul_rn(a0, v0), __fmul_rn(a1, v1)),
                                    __fmul_rn(a2, v2)),
                          __fmul_rn(a3, v3));
    float den = __fadd_rn(__fadd_rn(__fadd_rn(a0, a1), a2), a3);
    float denoised = __fdiv_rn(num, den);

    // where(primary, mean_x, where(~primary & s_cond, v_avg, denoised))
    return primary ? k1 : (s_cond ? vavg : denoised);
}

// x: (512, 256, 256) f32 viewed flat; out: (512, 128, 128) f32.
// Each thread: one float4 from row 2i and one from row 2i+1 -> two outputs.
__global__ void __launch_bounds__(256) fuzzy_kernel(const float* __restrict__ x,
                                                    float* __restrict__ out) {
    unsigned t = blockIdx.x * 256u + threadIdx.x;     // 0 .. 4194303
    unsigned jp = t & 63u;                             // float4 index within row (64 per row)
    unsigned i  = (t >> 6) & 127u;                     // output row
    unsigned bc = t >> 13;                             // channel (512)

    const float4* top = reinterpret_cast<const float4*>(
        x + (size_t)bc * 65536u + (size_t)(2u * i) * 256u) + jp;
    const float4* bot = top + 64;                      // next input row (256 floats)
    float4 a = *top;
    float4 b = *bot;

    float r0 = fuzzy_one(a.x, a.y, b.x, b.y);
    float r1 = fuzzy_one(a.z, a.w, b.z, b.w);

    float2* o = reinterpret_cast<float2*>(
        out + (size_t)bc * 16384u + (size_t)i * 128u) + jp;
    *o = make_float2(r0, r1);
}

extern "C" void kernel_launch(void* const* d_in, const int* in_sizes, int n_in,
                              void* d_out, int out_size, void* d_ws, size_t ws_size,
                              hipStream_t stream) {
    const float* x = (const float*)d_in[0];
    float* out = (float*)d_out;
    dim3 grid(16384), block(256);
    hipLaunchKernelGGL(fuzzy_kernel, grid, block, 0, stream, x, out);
}

// Round 2
// 29.722 us; speedup vs baseline: 2.1864x; 2.1864x over previous
//
#include <hip/hip_runtime.h>

#define EPSF 1e-4f

// Fast per-2x2-block computation. Same operation order as the numpy reference
// (so rounding drift stays small), but:
//   - v_rcp_f32 (__builtin_amdgcn_rcpf) instead of IEEE divide (divisors are
//     shared: 2 sigmas + 1 denominator per output, vs 9 full divides before)
//   - __expf (native v_exp_f32) instead of libm expf
//   - FMA contraction allowed
// Branch flips from the ~1e-6 rel perturbation are tolerated by the 5.8e-2
// absmax threshold (measured flip magnitude ~0.008 with exact arithmetic).
__device__ __forceinline__ float fuzzy_one(float v0, float v1, float v2, float v3) {
    float k0 = (v1 + v2) * 0.5f;
    float k1 = (((v0 + v1) + v2) + v3) * 0.25f;
    float vavg = (k0 + k1) * 0.5f;

    float o0 = fabsf(v0 - vavg);
    float o1 = fabsf(v1 - vavg);
    float o2 = fabsf(v2 - vavg);
    float o3 = fabsf(v3 - vavg);
    float sg0 = (o1 + o2) * 0.5f + EPSF;
    float sg1 = (((o0 + o1) + o2) + o3) * 0.25f + EPSF;

    float rs0 = __builtin_amdgcn_rcpf(sg0);   // v_rcp_f32
    float rs1 = __builtin_amdgcn_rcpf(sg1);
    // p = exp(-0.5 * ((v-k)*rs)^2); fold -0.5 into a per-k coefficient
    float c0 = -0.5f * rs0 * rs0;
    float c1 = -0.5f * rs1 * rs1;

    float dv00 = v0 - k0, dv01 = v1 - k0, dv02 = v2 - k0, dv03 = v3 - k0;
    float dv10 = v0 - k1, dv11 = v1 - k1, dv12 = v2 - k1, dv13 = v3 - k1;

    float p00 = __expf(dv00 * dv00 * c0);
    float p01 = __expf(dv01 * dv01 * c0);
    float p02 = __expf(dv02 * dv02 * c0);
    float p03 = __expf(dv03 * dv03 * c0);
    float p10 = __expf(dv10 * dv10 * c1);
    float p11 = __expf(dv11 * dv11 * c1);
    float p12 = __expf(dv12 * dv12 * c1);
    float p13 = __expf(dv13 * dv13 * c1);

    float a0 = (p00 + p10) * 0.5f;
    float a1 = (p01 + p11) * 0.5f;
    float a2 = (p02 + p12) * 0.5f;
    float a3 = (p03 + p13) * 0.5f;
    float pm0 = fmaxf(p00, p10);
    float pm1 = fmaxf(p01, p11);
    float pm2 = fmaxf(p02, p12);
    float pm3 = fmaxf(p03, p13);
    float thresh = fminf(fminf(fminf(pm0, pm1), pm2), pm3);

    bool primary = (a1 >= thresh);
    bool s_cond  = (sg1 < 0.001f);

    float num = ((a0 * v0 + a1 * v1) + a2 * v2) + a3 * v3;
    float den = ((a0 + a1) + a2) + a3;
    float denoised = num * __builtin_amdgcn_rcpf(den);

    return primary ? k1 : (s_cond ? vavg : denoised);
}

// x: (512, 256, 256) f32 flat; out: (512, 128, 128) f32.
// Each thread: one float4 from row 2i and one from row 2i+1 -> two outputs.
__global__ void __launch_bounds__(256) fuzzy_kernel(const float* __restrict__ x,
                                                    float* __restrict__ out) {
    unsigned t = blockIdx.x * 256u + threadIdx.x;     // 0 .. 4194303
    unsigned jp = t & 63u;                             // float4 index within row
    unsigned i  = (t >> 6) & 127u;                     // output row
    unsigned bc = t >> 13;                             // channel (512)

    const float4* top = reinterpret_cast<const float4*>(
        x + (size_t)bc * 65536u + (size_t)(2u * i) * 256u) + jp;
    const float4* bot = top + 64;                      // next input row
    float4 a = *top;
    float4 b = *bot;

    float r0 = fuzzy_one(a.x, a.y, b.x, b.y);
    float r1 = fuzzy_one(a.z, a.w, b.z, b.w);

    float2* o = reinterpret_cast<float2*>(
        out + (size_t)bc * 16384u + (size_t)i * 128u) + jp;
    *o = make_float2(r0, r1);
}

extern "C" void kernel_launch(void* const* d_in, const int* in_sizes, int n_in,
                              void* d_out, int out_size, void* d_ws, size_t ws_size,
                              hipStream_t stream) {
    const float* x = (const float*)d_in[0];
    float* out = (float*)d_out;
    dim3 grid(16384), block(256);
    hipLaunchKernelGGL(fuzzy_kernel, grid, block, 0, stream, x, out);
}